// Round 1
// baseline (270.282 us; speedup 1.0000x reference)
//
#include <hip/hip_runtime.h>
#include <math.h>

// AttentionCropLayer: mask = separable sigmoid box, then bilinear upsample of
// the crop [t-tl, t+tl)^2 to 224x224. Mask only matters at sampled positions,
// so fold mask into the bilinear weights.

constexpr int IMG = 224;
constexpr int ROWS_PER_TILE = 28;          // 224 / 8 tiles
constexpr int TILES = IMG / ROWS_PER_TILE; // 8

__device__ __forceinline__ float sigm10(float z) {
    // sigmoid(10*z); z is an exact small integer in fp32.
    return 1.0f / (1.0f + expf(-10.0f * z));
}

// Bilinear (align_corners=False) coeffs for output index j, crop center t,
// half-size tl. Replicates reference fp32 arithmetic exactly (_rn intrinsics
// prevent FMA contraction / fast-div so trunc/floor boundaries match).
__device__ __forceinline__ void coeffs(int j, int t, int tl,
                                       int& p0, int& p1,
                                       float& w, float& m0, float& m1) {
    const int in_size = 2 * tl;
    float src = __fsub_rn(
        __fdiv_rn(__fmul_rn((float)j + 0.5f, (float)in_size), 224.0f), 0.5f);
    src = fmaxf(src, 0.0f);
    const int i0 = (int)floorf(src);
    w = __fsub_rn(src, (float)i0);
    const int i1 = min(i0 + 1, in_size - 1);
    const int start = t - tl;
    p0 = start + i0;
    p1 = start + i1;
    const float tlf = (float)tl;
    const float d0 = (float)(p0 - t);
    const float d1 = (float)(p1 - t);
    m0 = sigm10(d0 + tlf) - sigm10(d0 - tlf);
    m1 = sigm10(d1 + tlf) - sigm10(d1 - tlf);
}

__global__ __launch_bounds__(256)
void attn_crop_kernel(const float* __restrict__ apn,
                      const float* __restrict__ in,
                      float* __restrict__ out) {
    __shared__ float4 rowc[ROWS_PER_TILE]; // {a, bw, bitcast(r0), bitcast(r1)}

    const int tid  = threadIdx.x;
    const int bid  = blockIdx.x;
    const int tile = bid & (TILES - 1);
    const int bc   = bid >> 3;              // b*3 + c, 0..767
    const int b    = bc / 3;

    // Per-batch crop parameters (exact reference fp32 arithmetic)
    const float a0 = apn[b * 3 + 0];
    const float a1 = apn[b * 3 + 1];
    const float a2 = apn[b * 3 + 2];
    const int tx = 112 + (int)truncf(__fadd_rn(__fmul_rn(a0, 56.0f), 0.5f));
    const int ty = 112 + (int)truncf(__fadd_rn(__fmul_rn(a1, 56.0f), 0.5f));
    const int tl = 38 + (int)truncf(
        __fmul_rn(__fmul_rn(__fadd_rn(a2, 1.0f), 0.5f), 18.0f));

    // Column coefficients: one column per thread, kept in registers.
    int c0 = 0, c1 = 0;
    float w00 = 0.0f, w01 = 0.0f;
    if (tid < IMG) {
        float wc, mc0, mc1;
        coeffs(tid, ty, tl, c0, c1, wc, mc0, mc1);
        w00 = (1.0f - wc) * mc0;
        w01 = wc * mc1;
    } else if (tid < IMG + ROWS_PER_TILE) {
        // Row coefficients for this tile's 28 rows -> LDS
        const int jj = tid - IMG;
        const int j  = tile * ROWS_PER_TILE + jj;
        int r0, r1;
        float wr, mr0, mr1;
        coeffs(j, tx, tl, r0, r1, wr, mr0, mr1);
        float4 rc;
        rc.x = (1.0f - wr) * mr0;            // a
        rc.y = wr * mr1;                     // bw
        rc.z = __int_as_float(r0);
        rc.w = __int_as_float(r1);
        rowc[jj] = rc;
    }
    __syncthreads();

    if (tid < IMG) {
        const float* inb = in + (size_t)bc * (IMG * IMG);
        float* outb = out + (size_t)bc * (IMG * IMG)
                          + (size_t)(tile * ROWS_PER_TILE) * IMG + tid;
#pragma unroll 4
        for (int jj = 0; jj < ROWS_PER_TILE; ++jj) {
            const float4 rc = rowc[jj];       // same-address broadcast
            const float a  = rc.x;
            const float bw = rc.y;
            const int r0 = __float_as_int(rc.z);
            const int r1 = __float_as_int(rc.w);
            const float* p0 = inb + r0 * IMG;
            const float* p1 = inb + r1 * IMG;
            const float v00 = p0[c0];
            const float v01 = p0[c1];
            const float v10 = p1[c0];
            const float v11 = p1[c1];
            const float t = w00 * v00 + w01 * v01;
            const float u = w00 * v10 + w01 * v11;
            outb[jj * IMG] = a * t + bw * u;
        }
    }
}

extern "C" void kernel_launch(void* const* d_in, const int* in_sizes, int n_in,
                              void* d_out, int out_size, void* d_ws, size_t ws_size,
                              hipStream_t stream) {
    const float* apn = (const float*)d_in[0];   // (256, 3)
    const float* in  = (const float*)d_in[1];   // (256, 3, 224, 224)
    float* out = (float*)d_out;                 // (256, 3, 224, 224)

    const int B = in_sizes[0] / 3;              // 256
    const int grid = B * 3 * TILES;             // 6144 blocks
    attn_crop_kernel<<<grid, 256, 0, stream>>>(apn, in, out);
}

// Round 2
// 256.143 us; speedup vs baseline: 1.0552x; 1.0552x over previous
//
#include <hip/hip_runtime.h>
#include <math.h>

// AttentionCropLayer v2: LDS-staged crop + separable mask folded into
// bilinear weights; each thread emits a float4 of output columns.
//
// Key facts: tl in [38,55] -> in_size=2*tl in [76,110]; crop always fully
// inside the 224x224 image (start >= 2, end <= 223). Upscale factor
// in_size/224 <= 0.492, so 4 consecutive output columns sample from <= 4
// consecutive input columns -> per-column 4-weight dot over one 4-float
// segment.

constexpr int IMG = 224;
constexpr int OUT_ROWS = 56;     // output rows per block
constexpr int TILES = IMG / OUT_ROWS;   // 4
constexpr int THREADS = 448;     // 7 waves; 56 col-groups x 8 rows
constexpr int STRIDE = 112;      // LDS row stride (floats), >= max in_size
constexpr int MAX_ROWS = 30;     // > ceil(56*110/224)+1

__device__ __forceinline__ float sigm10(float z) {
    return 1.0f / (1.0f + expf(-10.0f * z));
}

// Bilinear (align_corners=False) source indices for output j. Exact
// reference fp32 arithmetic (_rn blocks FMA contraction / fast-div so the
// floor/trunc boundaries match the reference bit-for-bit).
__device__ __forceinline__ void bilin_idx(int j, int tl, int& i0, int& i1, float& w) {
    const int in_size = 2 * tl;
    float src = __fsub_rn(
        __fdiv_rn(__fmul_rn((float)j + 0.5f, (float)in_size), 224.0f), 0.5f);
    src = fmaxf(src, 0.0f);
    i0 = (int)floorf(src);
    w = __fsub_rn(src, (float)i0);
    i1 = min(i0 + 1, in_size - 1);
}

// Full coeffs with mask folded in. p0/p1 are absolute image indices.
__device__ __forceinline__ void coeffs(int j, int t, int tl,
                                       int& p0, int& p1,
                                       float& w0, float& w1) {
    int i0, i1; float w;
    bilin_idx(j, tl, i0, i1, w);
    const int start = t - tl;
    p0 = start + i0;
    p1 = start + i1;
    const float tlf = (float)tl;
    const float d0 = (float)(p0 - t);
    const float d1 = (float)(p1 - t);
    const float m0 = sigm10(d0 + tlf) - sigm10(d0 - tlf);
    const float m1 = sigm10(d1 + tlf) - sigm10(d1 - tlf);
    w0 = (1.0f - w) * m0;
    w1 = w * m1;
}

__global__ __launch_bounds__(THREADS)
void attn_crop_kernel(const float* __restrict__ apn,
                      const float* __restrict__ in,
                      float* __restrict__ out) {
    __shared__ float  simg[MAX_ROWS * STRIDE];  // staged crop rows (13.4 KB)
    __shared__ float4 rowc[OUT_ROWS];           // {a, bw, r0idx, r1idx}
    __shared__ float4 colc[IMG];                // {w0, w1, c0loc, c1loc}

    const int tid  = threadIdx.x;
    const int bid  = blockIdx.x;
    const int tile = bid & (TILES - 1);
    const int bc   = bid >> 2;               // b*3 + c
    const int b    = bc / 3;

    const float a0 = apn[b * 3 + 0];
    const float a1 = apn[b * 3 + 1];
    const float a2 = apn[b * 3 + 2];
    const int tx = 112 + (int)truncf(__fadd_rn(__fmul_rn(a0, 56.0f), 0.5f));
    const int ty = 112 + (int)truncf(__fadd_rn(__fmul_rn(a1, 56.0f), 0.5f));
    const int tl = 38 + (int)truncf(
        __fmul_rn(__fmul_rn(__fadd_rn(a2, 1.0f), 0.5f), 18.0f));
    const int rowstart = tx - tl;
    const int colstart = ty - tl;

    // Staged row range for this tile (all threads compute; cheap, no expf).
    const int j0 = tile * OUT_ROWS;
    int loRow, hiRow;
    {
        int i0, i1; float w;
        bilin_idx(j0, tl, i0, i1, w);
        loRow = rowstart + i0;
        bilin_idx(j0 + OUT_ROWS - 1, tl, i0, i1, w);
        hiRow = rowstart + i1;
    }
    const int nRows = hiRow - loRow + 1;     // <= 29

    // Phase A: coefficient tables (threads 0..279) -----------------------
    if (tid < IMG) {
        int c0, c1; float w0, w1;
        coeffs(tid, ty, tl, c0, c1, w0, w1);
        float4 cc;
        cc.x = w0;
        cc.y = w1;
        cc.z = __int_as_float(c0 - colstart);     // local col index
        cc.w = __int_as_float(c1 - colstart);
        colc[tid] = cc;
    } else if (tid < IMG + OUT_ROWS) {
        const int j = j0 + (tid - IMG);
        int r0, r1; float w0, w1;
        coeffs(j, tx, tl, r0, r1, w0, w1);
        float4 rc;
        rc.x = w0;                                 // a
        rc.y = w1;                                 // bw
        rc.z = __int_as_float((r0 - loRow) * STRIDE);
        rc.w = __int_as_float((r1 - loRow) * STRIDE);
        rowc[tid - IMG] = rc;
    }

    // Phase B: stage crop rows into LDS (coalesced; all 112 cols, with the
    // global column clamped so pad slots get finite values -> 0-weights safe).
    const float* inb = in + (size_t)bc * (IMG * IMG);
    const int total = nRows * STRIDE;
    for (int idx = tid; idx < total; idx += THREADS) {
        const int r  = idx / STRIDE;              // const divisor -> magic mul
        const int c  = idx - r * STRIDE;
        const int gc = min(colstart + c, IMG - 1);
        simg[idx] = inb[(loRow + r) * IMG + gc];
    }
    __syncthreads();

    // Phase C: compute. g = column group (4 cols), rloc = row within pass.
    const int g    = tid % 56;
    const int rloc = tid / 56;

    const float4 cc0 = colc[4 * g + 0];
    const float4 cc1 = colc[4 * g + 1];
    const float4 cc2 = colc[4 * g + 2];
    const float4 cc3 = colc[4 * g + 3];
    const int base = __float_as_int(cc0.z);       // segment base (local col)

    // Per-column 4-weight vectors over segment [base, base+3].
    float4 wv0, wv1, wv2, wv3;
#define BUILD(WV, CC)                                                     \
    {                                                                     \
        const int o0 = __float_as_int(CC.z) - base;                       \
        const int o1 = __float_as_int(CC.w) - base;                       \
        const float w0 = CC.x, w1 = CC.y;                                 \
        WV.x = (o0 == 0 ? w0 : 0.0f) + (o1 == 0 ? w1 : 0.0f);             \
        WV.y = (o0 == 1 ? w0 : 0.0f) + (o1 == 1 ? w1 : 0.0f);             \
        WV.z = (o0 == 2 ? w0 : 0.0f) + (o1 == 2 ? w1 : 0.0f);             \
        WV.w = (o0 == 3 ? w0 : 0.0f) + (o1 == 3 ? w1 : 0.0f);             \
    }
    BUILD(wv0, cc0)
    BUILD(wv1, cc1)
    BUILD(wv2, cc2)
    BUILD(wv3, cc3)
#undef BUILD

    float* outb = out + (size_t)bc * (IMG * IMG) + (size_t)j0 * IMG + 4 * g;

#pragma unroll
    for (int pass = 0; pass < OUT_ROWS / 8; ++pass) {
        const int row = pass * 8 + rloc;
        const float4 rc = rowc[row];              // near-broadcast LDS read
        const float a  = rc.x;
        const float bw = rc.y;
        const float* s0 = simg + __float_as_int(rc.z) + base;
        const float* s1 = simg + __float_as_int(rc.w) + base;
        const float t0 = s0[0], t1 = s0[1], t2 = s0[2], t3 = s0[3];
        const float u0 = s1[0], u1 = s1[1], u2 = s1[2], u3 = s1[3];

        float4 o;
        o.x = a  * (wv0.x * t0 + wv0.y * t1 + wv0.z * t2 + wv0.w * t3)
            + bw * (wv0.x * u0 + wv0.y * u1 + wv0.z * u2 + wv0.w * u3);
        o.y = a  * (wv1.x * t0 + wv1.y * t1 + wv1.z * t2 + wv1.w * t3)
            + bw * (wv1.x * u0 + wv1.y * u1 + wv1.z * u2 + wv1.w * u3);
        o.z = a  * (wv2.x * t0 + wv2.y * t1 + wv2.z * t2 + wv2.w * t3)
            + bw * (wv2.x * u0 + wv2.y * u1 + wv2.z * u2 + wv2.w * u3);
        o.w = a  * (wv3.x * t0 + wv3.y * t1 + wv3.z * t2 + wv3.w * t3)
            + bw * (wv3.x * u0 + wv3.y * u1 + wv3.z * u2 + wv3.w * u3);

        *(float4*)(outb + row * IMG) = o;         // coalesced 16B store
    }
}

extern "C" void kernel_launch(void* const* d_in, const int* in_sizes, int n_in,
                              void* d_out, int out_size, void* d_ws, size_t ws_size,
                              hipStream_t stream) {
    const float* apn = (const float*)d_in[0];   // (256, 3)
    const float* in  = (const float*)d_in[1];   // (256, 3, 224, 224)
    float* out = (float*)d_out;                 // (256, 3, 224, 224)

    const int B = in_sizes[0] / 3;              // 256
    const int grid = B * 3 * TILES;             // 3072 blocks, 12 per CU
    attn_crop_kernel<<<grid, THREADS, 0, stream>>>(apn, in, out);
}

// Round 3
// 255.354 us; speedup vs baseline: 1.0585x; 1.0031x over previous
//
#include <hip/hip_runtime.h>
#include <math.h>

// AttentionCropLayer v3: LDS-staged crop + separable mask folded into
// bilinear weights; row-blend factored before column dots (VALU -40% in the
// hot loop vs v2). Each thread emits a float4 of output columns.
//
// Key facts: tl in [38,55] -> in_size=2*tl in [76,110]; crop always fully
// inside the 224x224 image. Upscale factor in_size/224 <= 0.492, so 4
// consecutive output columns sample from <= 4 consecutive input columns.

constexpr int IMG = 224;
constexpr int OUT_ROWS = 56;            // output rows per block
constexpr int TILES = IMG / OUT_ROWS;   // 4
constexpr int THREADS = 448;            // 7 waves; 56 col-groups x 8 rows
constexpr int STRIDE = 112;             // LDS row stride (floats) >= max in_size
constexpr int MAX_ROWS = 30;

__device__ __forceinline__ float sigm10(float z) {
    return 1.0f / (1.0f + expf(-10.0f * z));
}

// Bilinear (align_corners=False) source indices for output j. Exact
// reference fp32 arithmetic (_rn blocks FMA contraction / fast-div so the
// floor/trunc boundaries match the reference bit-for-bit).
__device__ __forceinline__ void bilin_idx(int j, int tl, int& i0, int& i1, float& w) {
    const int in_size = 2 * tl;
    float src = __fsub_rn(
        __fdiv_rn(__fmul_rn((float)j + 0.5f, (float)in_size), 224.0f), 0.5f);
    src = fmaxf(src, 0.0f);
    i0 = (int)floorf(src);
    w = __fsub_rn(src, (float)i0);
    i1 = min(i0 + 1, in_size - 1);
}

__device__ __forceinline__ void coeffs(int j, int t, int tl,
                                       int& p0, int& p1,
                                       float& w0, float& w1) {
    int i0, i1; float w;
    bilin_idx(j, tl, i0, i1, w);
    const int start = t - tl;
    p0 = start + i0;
    p1 = start + i1;
    const float tlf = (float)tl;
    const float d0 = (float)(p0 - t);
    const float d1 = (float)(p1 - t);
    const float m0 = sigm10(d0 + tlf) - sigm10(d0 - tlf);
    const float m1 = sigm10(d1 + tlf) - sigm10(d1 - tlf);
    w0 = (1.0f - w) * m0;
    w1 = w * m1;
}

__global__ __launch_bounds__(THREADS)
void attn_crop_kernel(const float* __restrict__ apn,
                      const float* __restrict__ in,
                      float* __restrict__ out) {
    __shared__ float  simg[MAX_ROWS * STRIDE];  // staged crop rows (13.4 KB)
    __shared__ float4 rowc[OUT_ROWS];           // {a, bw, r0off, r1off}
    __shared__ float4 colc[IMG];                // {w0, w1, c0loc, c1loc}

    const int tid  = threadIdx.x;
    const int bid  = blockIdx.x;
    const int tile = bid & (TILES - 1);
    const int bc   = bid >> 2;               // b*3 + c
    const int b    = bc / 3;

    const float a0 = apn[b * 3 + 0];
    const float a1 = apn[b * 3 + 1];
    const float a2 = apn[b * 3 + 2];
    const int tx = 112 + (int)truncf(__fadd_rn(__fmul_rn(a0, 56.0f), 0.5f));
    const int ty = 112 + (int)truncf(__fadd_rn(__fmul_rn(a1, 56.0f), 0.5f));
    const int tl = 38 + (int)truncf(
        __fmul_rn(__fmul_rn(__fadd_rn(a2, 1.0f), 0.5f), 18.0f));
    const int rowstart = tx - tl;
    const int colstart = ty - tl;

    // Staged input-row range for this tile.
    const int j0 = tile * OUT_ROWS;
    int loRow, hiRow;
    {
        int i0, i1; float w;
        bilin_idx(j0, tl, i0, i1, w);
        loRow = rowstart + i0;
        bilin_idx(j0 + OUT_ROWS - 1, tl, i0, i1, w);
        hiRow = rowstart + i1;
    }
    const int nRows = hiRow - loRow + 1;     // <= 29

    // Phase A: coefficient tables.
    if (tid < IMG) {
        int c0, c1; float w0, w1;
        coeffs(tid, ty, tl, c0, c1, w0, w1);
        float4 cc;
        cc.x = w0;
        cc.y = w1;
        cc.z = __int_as_float(c0 - colstart);
        cc.w = __int_as_float(c1 - colstart);
        colc[tid] = cc;
    } else if (tid < IMG + OUT_ROWS) {
        const int j = j0 + (tid - IMG);
        int r0, r1; float w0, w1;
        coeffs(j, tx, tl, r0, r1, w0, w1);
        float4 rc;
        rc.x = w0;                                 // a
        rc.y = w1;                                 // bw
        rc.z = __int_as_float((r0 - loRow) * STRIDE);
        rc.w = __int_as_float((r1 - loRow) * STRIDE);
        rowc[tid - IMG] = rc;
    }

    // Phase B: stage crop rows into LDS (coalesced; pad cols clamped so the
    // 0-weight slots read finite values).
    const float* inb = in + (size_t)bc * (IMG * IMG);
    const int total = nRows * STRIDE;
    for (int idx = tid; idx < total; idx += THREADS) {
        const int r  = idx / STRIDE;               // const divisor -> magic mul
        const int c  = idx - r * STRIDE;
        const int gc = min(colstart + c, IMG - 1);
        simg[idx] = inb[(loRow + r) * IMG + gc];
    }
    __syncthreads();

    // Phase C: g = column group (4 output cols), rloc = row slot within pass.
    const int g    = tid % 56;
    const int rloc = tid / 56;

    const float4 cc0 = colc[4 * g + 0];
    const float4 cc1 = colc[4 * g + 1];
    const float4 cc2 = colc[4 * g + 2];
    const float4 cc3 = colc[4 * g + 3];
    const int base = __float_as_int(cc0.z);        // segment base (local col)

    // Per-column 4-weight vectors over segment [base, base+3].
    float4 wv0, wv1, wv2, wv3;
#define BUILD(WV, CC)                                                     \
    {                                                                     \
        const int o0 = __float_as_int(CC.z) - base;                       \
        const int o1 = __float_as_int(CC.w) - base;                       \
        const float w0 = CC.x, w1 = CC.y;                                 \
        WV.x = (o0 == 0 ? w0 : 0.0f) + (o1 == 0 ? w1 : 0.0f);             \
        WV.y = (o0 == 1 ? w0 : 0.0f) + (o1 == 1 ? w1 : 0.0f);             \
        WV.z = (o0 == 2 ? w0 : 0.0f) + (o1 == 2 ? w1 : 0.0f);             \
        WV.w = (o0 == 3 ? w0 : 0.0f) + (o1 == 3 ? w1 : 0.0f);             \
    }
    BUILD(wv0, cc0)
    BUILD(wv1, cc1)
    BUILD(wv2, cc2)
    BUILD(wv3, cc3)
#undef BUILD

    float* outb = out + (size_t)bc * (IMG * IMG) + (size_t)j0 * IMG + 4 * g;

#pragma unroll
    for (int pass = 0; pass < OUT_ROWS / 8; ++pass) {
        const int row = pass * 8 + rloc;
        const float4 rc = rowc[row];               // 2 addresses/wave LDS read
        const float a  = rc.x;
        const float bw = rc.y;
        const float* s0 = simg + __float_as_int(rc.z) + base;
        const float* s1 = simg + __float_as_int(rc.w) + base;

        // Row blend first (independent of column), then 4-tap column dots.
        const float m0 = a * s0[0] + bw * s1[0];
        const float m1 = a * s0[1] + bw * s1[1];
        const float m2 = a * s0[2] + bw * s1[2];
        const float m3 = a * s0[3] + bw * s1[3];

        float4 o;
        o.x = wv0.x * m0 + wv0.y * m1 + wv0.z * m2 + wv0.w * m3;
        o.y = wv1.x * m0 + wv1.y * m1 + wv1.z * m2 + wv1.w * m3;
        o.z = wv2.x * m0 + wv2.y * m1 + wv2.z * m2 + wv2.w * m3;
        o.w = wv3.x * m0 + wv3.y * m1 + wv3.z * m2 + wv3.w * m3;

        *(float4*)(outb + row * IMG) = o;          // coalesced 16B store
    }
}

extern "C" void kernel_launch(void* const* d_in, const int* in_sizes, int n_in,
                              void* d_out, int out_size, void* d_ws, size_t ws_size,
                              hipStream_t stream) {
    const float* apn = (const float*)d_in[0];   // (256, 3)
    const float* in  = (const float*)d_in[1];   // (256, 3, 224, 224)
    float* out = (float*)d_out;                 // (256, 3, 224, 224)

    const int B = in_sizes[0] / 3;              // 256
    const int grid = B * 3 * TILES;             // 3072 blocks
    attn_crop_kernel<<<grid, THREADS, 0, stream>>>(apn, in, out);
}